// Round 11
// baseline (233.974 us; speedup 1.0000x reference)
//
#include <hip/hip_runtime.h>
#include <hip/hip_bf16.h>

// Problem: B=2, T=2048, C=1024, H=16, D=64. Tensors stored f32; compute bf16 MFMA.
#define Bb 2
#define Tt 2048
#define Cc 1024
#define Hh 16
#define Dd 64

typedef __bf16 bf16x8 __attribute__((ext_vector_type(8)));
typedef __bf16 bf16x4 __attribute__((ext_vector_type(4)));
typedef float f32x4 __attribute__((ext_vector_type(4)));

#define MFMA16(a, b, c) __builtin_amdgcn_mfma_f32_16x16x32_bf16((a), (b), (c), 0, 0, 0)

__device__ __forceinline__ bf16x8 ldg8(const __hip_bfloat16* p) {
  return *reinterpret_cast<const bf16x8*>(p);
}
__device__ __forceinline__ bf16x8 lds8(const __bf16* p) {
  return *reinterpret_cast<const bf16x8*>(p);
}

// Async global->LDS, 16B per lane. LDS dest = wave-uniform base + lane*16.
__device__ __forceinline__ void load_lds16(const __hip_bfloat16* g, __hip_bfloat16* l) {
  __builtin_amdgcn_global_load_lds(
      (const __attribute__((address_space(1))) void*)g,
      (__attribute__((address_space(3))) void*)l, 16, 0, 0);
}

// ---------------------------------------------------------------------------
// Merged weight transpose+cast: W_qkv f32[1024,3072] -> bf16[3072,1024] and
// W_proj f32[1024,1024] -> bf16[1024,1024], one kernel (blockIdx.x dispatch).
// ---------------------------------------------------------------------------
__global__ __launch_bounds__(256) void prep_weights(
    const float* __restrict__ Wq, const float* __restrict__ Wp,
    __hip_bfloat16* __restrict__ WTq, __hip_bfloat16* __restrict__ WTp) {
  __shared__ float tile[32][33];
  const bool isQ = blockIdx.x < 96;
  const float* in = isQ ? Wq : Wp;
  __hip_bfloat16* out = isQ ? WTq : WTp;
  const int Cn = isQ ? 3 * Cc : Cc;
  const int c0 = (isQ ? blockIdx.x : blockIdx.x - 96) * 32;
  const int r0 = blockIdx.y * 32;
  const int tx = threadIdx.x, ty = threadIdx.y;  // block (32,8)
#pragma unroll
  for (int i = 0; i < 32; i += 8)
    tile[ty + i][tx] = in[(size_t)(r0 + ty + i) * Cn + c0 + tx];
  __syncthreads();
#pragma unroll
  for (int i = 0; i < 32; i += 8)
    out[(size_t)(c0 + ty + i) * Cc + r0 + tx] = __float2bfloat16(tile[tx][ty + i]);
}

// ---------------------------------------------------------------------------
// QKV GEMM (m97 structure, fused x-cast): x f32[4096,1024] @ WT[3072,1024]^T + b
//   -> Q,K [B,H,T,D] bf16, V^T [B,H,D,T] bf16
// A-tile staged via f32 vector loads + register cvt + ds_write_b128 (layout
// identical to the global_load_lds version); B-tile via global_load_lds.
// ---------------------------------------------------------------------------
__global__ __launch_bounds__(256) void qkv_gemm(
    const float* __restrict__ x, const __hip_bfloat16* __restrict__ WT,
    const float* __restrict__ bias,
    __hip_bfloat16* __restrict__ Q, __hip_bfloat16* __restrict__ Kd,
    __hip_bfloat16* __restrict__ VT) {
  __shared__ __hip_bfloat16 As[128 * 32];
  __shared__ __hip_bfloat16 Bs[128 * 32];
  const int tid = threadIdx.x;
  const int wave = tid >> 6, lane = tid & 63;
  const int l16 = lane & 15, quad = lane >> 4;
  const int m0 = blockIdx.y * 128, n0 = blockIdx.x * 128;
  const int wm = (wave >> 1) * 64, wn = (wave & 1) * 64;

  const int srow = wave * 32 + (lane >> 2);  // B staging row (+16 for j=1)
  const int kseg = (lane & 3) * 8;

  const int arow = tid >> 1;           // 0..127 (A staging row)
  const int akseg = (tid & 1) * 16;    // 0 or 16

  f32x4 acc[4][4] = {};

  for (int k0 = 0; k0 < Cc; k0 += 32) {
    __syncthreads();
    // A-tile: 16 f32 -> 16 bf16 per thread, two ds_write_b128.
    {
      const float* xr = x + (size_t)(m0 + arow) * Cc + k0 + akseg;
      const f32x4 f0 = *reinterpret_cast<const f32x4*>(xr);
      const f32x4 f1 = *reinterpret_cast<const f32x4*>(xr + 4);
      const f32x4 f2 = *reinterpret_cast<const f32x4*>(xr + 8);
      const f32x4 f3 = *reinterpret_cast<const f32x4*>(xr + 12);
      bf16x8 c0, c1;
#pragma unroll
      for (int e = 0; e < 4; ++e) {
        c0[e] = (__bf16)f0[e];
        c0[4 + e] = (__bf16)f1[e];
        c1[e] = (__bf16)f2[e];
        c1[4 + e] = (__bf16)f3[e];
      }
      *reinterpret_cast<bf16x8*>(As + arow * 32 + akseg) = c0;
      *reinterpret_cast<bf16x8*>(As + arow * 32 + akseg + 8) = c1;
    }
    // B-tile: async global->LDS.
#pragma unroll
    for (int j = 0; j < 2; ++j)
      load_lds16(WT + (size_t)(n0 + srow + j * 16) * Cc + k0 + kseg,
                 Bs + (wave * 32 + j * 16) * 32);
    __syncthreads();

    bf16x8 af[4], bfr[4];
#pragma unroll
    for (int i = 0; i < 4; ++i) {
      af[i] = lds8((__bf16*)As + (wm + i * 16 + l16) * 32 + quad * 8);
      bfr[i] = lds8((__bf16*)Bs + (wn + i * 16 + l16) * 32 + quad * 8);
    }
#pragma unroll
    for (int i = 0; i < 4; ++i)
#pragma unroll
      for (int jn = 0; jn < 4; ++jn)
        acc[i][jn] = MFMA16(af[i], bfr[jn], acc[i][jn]);
  }

  const int sect = n0 >> 10;  // 0=Q 1=K 2=V (uniform per block)
#pragma unroll
  for (int jn = 0; jn < 4; ++jn) {
    const int n = n0 + wn + jn * 16 + l16;
    const float bv = bias[n];
    const int ch = n & 1023;
    const int h = ch >> 6, d = ch & 63;
#pragma unroll
    for (int i = 0; i < 4; ++i) {
#pragma unroll
      for (int r = 0; r < 4; ++r) {
        const int m = m0 + wm + i * 16 + quad * 4 + r;
        const int b = m >> 11, t = m & 2047;
        const __hip_bfloat16 o = __float2bfloat16(acc[i][jn][r] + bv);
        const int bh = b * Hh + h;
        if (sect == 0)      Q[((size_t)bh * Tt + t) * Dd + d] = o;
        else if (sect == 1) Kd[((size_t)bh * Tt + t) * Dd + d] = o;
        else                VT[((size_t)bh * Dd + d) * Tt + t] = o;
      }
    }
  }
}

// ---------------------------------------------------------------------------
// Flash attention v8 (unchanged from R10): static-max softmax, merged causal
// pair {qb, 31-qb}, register prefetch, shared K/V LDS reads for both chains.
// ---------------------------------------------------------------------------
__global__ __launch_bounds__(256, 2) void attn(
    const __hip_bfloat16* __restrict__ Q, const __hip_bfloat16* __restrict__ K,
    const __hip_bfloat16* __restrict__ VT, __hip_bfloat16* __restrict__ O) {
  const int tid = threadIdx.x;
  const int wave = tid >> 6, lane = tid & 63;
  const int l16 = lane & 15, quad = lane >> 4;
  const int bh = blockIdx.z * Hh + blockIdx.y;

  const __hip_bfloat16* Qh = Q + (size_t)bh * Tt * Dd;
  const __hip_bfloat16* Kh = K + (size_t)bh * Tt * Dd;
  const __hip_bfloat16* Vh = VT + (size_t)bh * Dd * Tt;
  __hip_bfloat16* Oh = O + (size_t)bh * Tt * Dd;

  __shared__ __align__(16) __bf16 Kt[64 * 72];
  __shared__ __align__(16) __bf16 Vt[64 * 72];
  __shared__ __align__(16) __bf16 Pt[4][2][16 * 72];  // [wave][chain B=0,A=1]

  const float SC = 0.18033688011112042f;  // (1/sqrt(64)) * log2(e)
  const int skey = tid >> 3, sd = (tid & 7) * 8;

  const int qbA = blockIdx.x;           // near q-tile (64-row units)
  const int qbB = (Tt / 64 - 1) - qbA;  // far q-tile
  const int qrowA = qbA * 64 + wave * 16 + l16;
  const int qrowB = qbB * 64 + wave * 16 + l16;

  const bf16x8 qA0 = ldg8(Qh + (size_t)qrowA * Dd + quad * 8);
  const bf16x8 qA1 = ldg8(Qh + (size_t)qrowA * Dd + 32 + quad * 8);
  const bf16x8 qB0 = ldg8(Qh + (size_t)qrowB * Dd + quad * 8);
  const bf16x8 qB1 = ldg8(Qh + (size_t)qrowB * Dd + 32 + quad * 8);

  f32x4 oA[4] = {}, oB[4] = {};
  float lA = 0.f, lB = 0.f;  // per-lane partial denominators

  const int nkB = qbB + 1;

  // Prologue prefetch (tile 0).
  bf16x8 ka = ldg8(Kh + (size_t)skey * Dd + sd);
  bf16x8 kb = ldg8(Kh + (size_t)(32 + skey) * Dd + sd);
  bf16x8 va = ldg8(Vh + (size_t)skey * Tt + sd);
  bf16x8 vb = ldg8(Vh + (size_t)(32 + skey) * Tt + sd);

  for (int kt0 = 0; kt0 < nkB; ++kt0) {
    const int k0 = kt0 * 64;
    __syncthreads();  // all waves done reading previous Kt/Vt
    *reinterpret_cast<bf16x8*>(&Kt[skey * 72 + sd]) = ka;
    *reinterpret_cast<bf16x8*>(&Kt[(32 + skey) * 72 + sd]) = kb;
    *reinterpret_cast<bf16x8*>(&Vt[skey * 72 + sd]) = va;
    *reinterpret_cast<bf16x8*>(&Vt[(32 + skey) * 72 + sd]) = vb;
    if (kt0 + 1 < nkB) {  // prefetch next tile; completes during compute
      const int k1 = k0 + 64;
      ka = ldg8(Kh + (size_t)(k1 + skey) * Dd + sd);
      kb = ldg8(Kh + (size_t)(k1 + 32 + skey) * Dd + sd);
      va = ldg8(Vh + (size_t)skey * Tt + k1 + sd);
      vb = ldg8(Vh + (size_t)(32 + skey) * Tt + k1 + sd);
    }
    __syncthreads();

    const bool doA = (kt0 <= qbA);
    const bool diagB = (kt0 == qbB), diagA = (kt0 == qbA);

    // Shared K fragment reads; S^T = K·Q^T for both chains.
    f32x4 stB[4], stA[4];
#pragma unroll
    for (int kt = 0; kt < 4; ++kt) {
      const __bf16* kr = &Kt[(kt * 16 + l16) * 72 + quad * 8];
      const bf16x8 k0f = lds8(kr), k1f = lds8(kr + 32);
      f32x4 zb = {};
      zb = MFMA16(k0f, qB0, zb);
      stB[kt] = MFMA16(k1f, qB1, zb);
      if (doA) {
        f32x4 za = {};
        za = MFMA16(k0f, qA0, za);
        stA[kt] = MFMA16(k1f, qA1, za);
      }
    }

    // ---- chain B: p = exp2(s*SC) (static max M=0), mask on diag only ----
#pragma unroll
    for (int kt = 0; kt < 4; ++kt) {
      bf16x4 pk;
#pragma unroll
      for (int r = 0; r < 4; ++r) {
        float p = exp2f(stB[kt][r] * SC);
        if (diagB) {
          const int key = k0 + kt * 16 + quad * 4 + r;
          p = (key <= qrowB) ? p : 0.f;
        }
        lB += p;
        pk[r] = (__bf16)p;
      }
      *reinterpret_cast<bf16x4*>(&Pt[wave][0][l16 * 72 + kt * 16 + quad * 4]) = pk;
    }

    // ---- chain A ----
    if (doA) {
#pragma unroll
      for (int kt = 0; kt < 4; ++kt) {
        bf16x4 pk;
#pragma unroll
        for (int r = 0; r < 4; ++r) {
          float p = exp2f(stA[kt][r] * SC);
          if (diagA) {
            const int key = k0 + kt * 16 + quad * 4 + r;
            p = (key <= qrowA) ? p : 0.f;
          }
          lA += p;
          pk[r] = (__bf16)p;
        }
        *reinterpret_cast<bf16x4*>(&Pt[wave][1][l16 * 72 + kt * 16 + quad * 4]) = pk;
      }
    }

    // ---- PV for both chains, sharing V fragment reads ----
    const bf16x8 pB0 = lds8(&Pt[wave][0][l16 * 72 + quad * 8]);
    const bf16x8 pB1 = lds8(&Pt[wave][0][l16 * 72 + 32 + quad * 8]);
    const bf16x8 pA0 = lds8(&Pt[wave][1][l16 * 72 + quad * 8]);
    const bf16x8 pA1 = lds8(&Pt[wave][1][l16 * 72 + 32 + quad * 8]);
#pragma unroll
    for (int dt = 0; dt < 4; ++dt) {
      const __bf16* vr = &Vt[(dt * 16 + l16) * 72];
      const bf16x8 v0f = lds8(vr + quad * 8), v1f = lds8(vr + 32 + quad * 8);
      oB[dt] = MFMA16(v0f, pB0, oB[dt]);
      oB[dt] = MFMA16(v1f, pB1, oB[dt]);
      if (doA) {
        oA[dt] = MFMA16(v0f, pA0, oA[dt]);
        oA[dt] = MFMA16(v1f, pA1, oA[dt]);
      }
    }
  }

  // One cross-lane reduction per chain for the denominators.
  lA += __shfl_xor(lA, 16, 64);
  lA += __shfl_xor(lA, 32, 64);
  lB += __shfl_xor(lB, 16, 64);
  lB += __shfl_xor(lB, 32, 64);

  const float invA = 1.f / lA, invB = 1.f / lB;
#pragma unroll
  for (int dt = 0; dt < 4; ++dt) {
    bf16x4 ovA, ovB;
#pragma unroll
    for (int r = 0; r < 4; ++r) {
      ovA[r] = (__bf16)(oA[dt][r] * invA);
      ovB[r] = (__bf16)(oB[dt][r] * invB);
    }
    *reinterpret_cast<bf16x4*>(&Oh[(size_t)qrowA * Dd + dt * 16 + quad * 4]) = ovA;
    *reinterpret_cast<bf16x4*>(&Oh[(size_t)qrowB * Dd + dt * 16 + quad * 4]) = ovB;
  }
}

// ---------------------------------------------------------------------------
// Proj GEMM (m97 structure): y(f32)[4096,1024] = O([B,H,T,D]) @ WT[1024,1024]^T + b
// ---------------------------------------------------------------------------
__global__ __launch_bounds__(256) void proj_gemm(
    const __hip_bfloat16* __restrict__ O, const __hip_bfloat16* __restrict__ WT,
    const float* __restrict__ bias, float* __restrict__ out) {
  __shared__ __hip_bfloat16 As[128 * 32];
  __shared__ __hip_bfloat16 Bs[128 * 32];
  const int tid = threadIdx.x;
  const int wave = tid >> 6, lane = tid & 63;
  const int l16 = lane & 15, quad = lane >> 4;
  const int m0 = blockIdx.y * 128, n0 = blockIdx.x * 128;
  const int wm = (wave >> 1) * 64, wn = (wave & 1) * 64;

  const int srow = wave * 32 + (lane >> 2);
  const int kseg = (lane & 3) * 8;

  f32x4 acc[4][4] = {};

  for (int k0 = 0; k0 < Cc; k0 += 32) {
    const int k = k0 + kseg;  // channel = h*64+d; 8-seg never crosses a head
    const int h = k >> 6, d = k & 63;
    __syncthreads();
#pragma unroll
    for (int j = 0; j < 2; ++j) {
      const int m = m0 + srow + j * 16;
      const int b = m >> 11, t = m & 2047;
      load_lds16(O + ((size_t)(b * Hh + h) * Tt + t) * Dd + d,
                 As + (wave * 32 + j * 16) * 32);
      load_lds16(WT + (size_t)(n0 + srow + j * 16) * Cc + k0 + kseg,
                 Bs + (wave * 32 + j * 16) * 32);
    }
    __syncthreads();

    bf16x8 af[4], bfr[4];
#pragma unroll
    for (int i = 0; i < 4; ++i) {
      af[i] = ldg8(As + (wm + i * 16 + l16) * 32 + quad * 8);
      bfr[i] = ldg8(Bs + (wn + i * 16 + l16) * 32 + quad * 8);
    }
#pragma unroll
    for (int i = 0; i < 4; ++i)
#pragma unroll
      for (int jn = 0; jn < 4; ++jn)
        acc[i][jn] = MFMA16(af[i], bfr[jn], acc[i][jn]);
  }

#pragma unroll
  for (int jn = 0; jn < 4; ++jn) {
    const int n = n0 + wn + jn * 16 + l16;
    const float bv = bias[n];
#pragma unroll
    for (int i = 0; i < 4; ++i)
#pragma unroll
      for (int r = 0; r < 4; ++r) {
        const int m = m0 + wm + i * 16 + quad * 4 + r;
        out[(size_t)m * Cc + n] = acc[i][jn][r] + bv;
      }
  }
}

// ---------------------------------------------------------------------------
extern "C" void kernel_launch(void* const* d_in, const int* in_sizes, int n_in,
                              void* d_out, int out_size, void* d_ws, size_t ws_size,
                              hipStream_t stream) {
  const float* x      = (const float*)d_in[0];
  const float* W_qkv  = (const float*)d_in[1];
  const float* b_qkv  = (const float*)d_in[2];
  const float* W_proj = (const float*)d_in[3];
  const float* b_proj = (const float*)d_in[4];
  float* out = (float*)d_out;

  __hip_bfloat16* ws = (__hip_bfloat16*)d_ws;
  const size_t NBHTD = (size_t)Bb * Hh * Tt * Dd;  // 4,194,304
  __hip_bfloat16* Qw  = ws;
  __hip_bfloat16* Kw  = ws + NBHTD;
  __hip_bfloat16* VTw = ws + 2 * NBHTD;
  __hip_bfloat16* Ow  = ws + 3 * NBHTD;
  __hip_bfloat16* WTqkv  = ws + 4 * NBHTD;               // [3072,1024]
  __hip_bfloat16* WTproj = WTqkv + (size_t)3 * Cc * Cc;  // [1024,1024]

  prep_weights<<<dim3(128, 32), dim3(32, 8), 0, stream>>>(W_qkv, W_proj, WTqkv, WTproj);
  qkv_gemm<<<dim3(24, 32), 256, 0, stream>>>(x, WTqkv, b_qkv, Qw, Kw, VTw);
  attn<<<dim3(Tt / 128, Hh, Bb), 256, 0, stream>>>(Qw, Kw, VTw, Ow);
  proj_gemm<<<dim3(8, 32), 256, 0, stream>>>(Ow, WTproj, b_proj, out);
}

// Round 12
// 214.153 us; speedup vs baseline: 1.0926x; 1.0926x over previous
//
#include <hip/hip_runtime.h>
#include <hip/hip_bf16.h>

// Problem: B=2, T=2048, C=1024, H=16, D=64. Tensors stored f32; compute bf16 MFMA.
#define Bb 2
#define Tt 2048
#define Cc 1024
#define Hh 16
#define Dd 64

typedef __bf16 bf16x8 __attribute__((ext_vector_type(8)));
typedef __bf16 bf16x4 __attribute__((ext_vector_type(4)));
typedef float f32x4 __attribute__((ext_vector_type(4)));

#define MFMA16(a, b, c) __builtin_amdgcn_mfma_f32_16x16x32_bf16((a), (b), (c), 0, 0, 0)

__device__ __forceinline__ bf16x8 ldg8(const __hip_bfloat16* p) {
  return *reinterpret_cast<const bf16x8*>(p);
}
__device__ __forceinline__ bf16x8 lds8(const __bf16* p) {
  return *reinterpret_cast<const bf16x8*>(p);
}

// Async global->LDS, 16B per lane. LDS dest = wave-uniform base + lane*16.
__device__ __forceinline__ void load_lds16(const __hip_bfloat16* g, __hip_bfloat16* l) {
  __builtin_amdgcn_global_load_lds(
      (const __attribute__((address_space(1))) void*)g,
      (__attribute__((address_space(3))) void*)l, 16, 0, 0);
}

// ---------------------------------------------------------------------------
// Merged weight transpose+cast: W_qkv f32[1024,3072] -> bf16[3072,1024] and
// W_proj f32[1024,1024] -> bf16[1024,1024], one kernel (blockIdx.x dispatch).
// ---------------------------------------------------------------------------
__global__ __launch_bounds__(256) void prep_weights(
    const float* __restrict__ Wq, const float* __restrict__ Wp,
    __hip_bfloat16* __restrict__ WTq, __hip_bfloat16* __restrict__ WTp) {
  __shared__ float tile[32][33];
  const bool isQ = blockIdx.x < 96;
  const float* in = isQ ? Wq : Wp;
  __hip_bfloat16* out = isQ ? WTq : WTp;
  const int Cn = isQ ? 3 * Cc : Cc;
  const int c0 = (isQ ? blockIdx.x : blockIdx.x - 96) * 32;
  const int r0 = blockIdx.y * 32;
  const int tx = threadIdx.x, ty = threadIdx.y;  // block (32,8)
#pragma unroll
  for (int i = 0; i < 32; i += 8)
    tile[ty + i][tx] = in[(size_t)(r0 + ty + i) * Cn + c0 + tx];
  __syncthreads();
#pragma unroll
  for (int i = 0; i < 32; i += 8)
    out[(size_t)(c0 + ty + i) * Cc + r0 + tx] = __float2bfloat16(tile[tx][ty + i]);
}

// ---------------------------------------------------------------------------
// QKV GEMM (m97 structure, fused x-cast v2): x f32[4096,1024] @ WT^T + b
//   -> Q,K [B,H,T,D] bf16, V^T [B,H,D,T] bf16
// A-tile: conflict-free linear LDS writes (thread t -> byte t*16, +4KB) from
// REGISTER-PREFETCHED f32 (loads issued previous iter, ride through barrier).
// B-tile: global_load_lds. Fixes R11's 4.7M bank conflicts + exposed latency.
// ---------------------------------------------------------------------------
__global__ __launch_bounds__(256) void qkv_gemm(
    const float* __restrict__ x, const __hip_bfloat16* __restrict__ WT,
    const float* __restrict__ bias,
    __hip_bfloat16* __restrict__ Q, __hip_bfloat16* __restrict__ Kd,
    __hip_bfloat16* __restrict__ VT) {
  __shared__ __hip_bfloat16 As[128 * 32];
  __shared__ __hip_bfloat16 Bs[128 * 32];
  const int tid = threadIdx.x;
  const int wave = tid >> 6, lane = tid & 63;
  const int l16 = lane & 15, quad = lane >> 4;
  const int m0 = blockIdx.y * 128, n0 = blockIdx.x * 128;
  const int wm = (wave >> 1) * 64, wn = (wave & 1) * 64;

  const int srow = wave * 32 + (lane >> 2);  // B staging row (+16 for j=1)
  const int kseg = (lane & 3) * 8;

  // A staging: linear conflict-free mapping. Thread t covers
  // rows ar and 64+ar, elems as..as+7 (16B chunks at byte t*16 and t*16+4096).
  const int ar = tid >> 2;         // 0..63
  const int as = (tid & 3) * 8;    // 0,8,16,24

  f32x4 acc[4][4] = {};

  // Prologue prefetch of x tile k0=0 (register loads - NOT drained by barrier).
  const float* xr0 = x + (size_t)(m0 + ar) * Cc + as;
  const float* xr1 = x + (size_t)(m0 + 64 + ar) * Cc + as;
  f32x4 f0 = *reinterpret_cast<const f32x4*>(xr0);
  f32x4 f1 = *reinterpret_cast<const f32x4*>(xr0 + 4);
  f32x4 f2 = *reinterpret_cast<const f32x4*>(xr1);
  f32x4 f3 = *reinterpret_cast<const f32x4*>(xr1 + 4);

  for (int k0 = 0; k0 < Cc; k0 += 32) {
    __syncthreads();
    // A-tile: cvt prefetched f32 -> bf16, two conflict-free ds_write_b128.
    {
      bf16x8 c0, c1;
#pragma unroll
      for (int e = 0; e < 4; ++e) {
        c0[e] = (__bf16)f0[e];
        c0[4 + e] = (__bf16)f1[e];
        c1[e] = (__bf16)f2[e];
        c1[4 + e] = (__bf16)f3[e];
      }
      *reinterpret_cast<bf16x8*>(As + ar * 32 + as) = c0;
      *reinterpret_cast<bf16x8*>(As + (64 + ar) * 32 + as) = c1;
    }
    // B-tile: async global->LDS.
#pragma unroll
    for (int j = 0; j < 2; ++j)
      load_lds16(WT + (size_t)(n0 + srow + j * 16) * Cc + k0 + kseg,
                 Bs + (wave * 32 + j * 16) * 32);
    // Prefetch next x tile into registers (overlaps compute below).
    if (k0 + 32 < Cc) {
      f0 = *reinterpret_cast<const f32x4*>(xr0 + k0 + 32);
      f1 = *reinterpret_cast<const f32x4*>(xr0 + k0 + 36);
      f2 = *reinterpret_cast<const f32x4*>(xr1 + k0 + 32);
      f3 = *reinterpret_cast<const f32x4*>(xr1 + k0 + 36);
    }
    __syncthreads();

    bf16x8 af[4], bfr[4];
#pragma unroll
    for (int i = 0; i < 4; ++i) {
      af[i] = lds8((__bf16*)As + (wm + i * 16 + l16) * 32 + quad * 8);
      bfr[i] = lds8((__bf16*)Bs + (wn + i * 16 + l16) * 32 + quad * 8);
    }
#pragma unroll
    for (int i = 0; i < 4; ++i)
#pragma unroll
      for (int jn = 0; jn < 4; ++jn)
        acc[i][jn] = MFMA16(af[i], bfr[jn], acc[i][jn]);
  }

  const int sect = n0 >> 10;  // 0=Q 1=K 2=V (uniform per block)
#pragma unroll
  for (int jn = 0; jn < 4; ++jn) {
    const int n = n0 + wn + jn * 16 + l16;
    const float bv = bias[n];
    const int ch = n & 1023;
    const int h = ch >> 6, d = ch & 63;
#pragma unroll
    for (int i = 0; i < 4; ++i) {
#pragma unroll
      for (int r = 0; r < 4; ++r) {
        const int m = m0 + wm + i * 16 + quad * 4 + r;
        const int b = m >> 11, t = m & 2047;
        const __hip_bfloat16 o = __float2bfloat16(acc[i][jn][r] + bv);
        const int bh = b * Hh + h;
        if (sect == 0)      Q[((size_t)bh * Tt + t) * Dd + d] = o;
        else if (sect == 1) Kd[((size_t)bh * Tt + t) * Dd + d] = o;
        else                VT[((size_t)bh * Dd + d) * Tt + t] = o;
      }
    }
  }
}

// ---------------------------------------------------------------------------
// Flash attention v8 (unchanged): static-max softmax, merged causal pair
// {qb, 31-qb}, register prefetch, shared K/V LDS reads for both chains.
// ---------------------------------------------------------------------------
__global__ __launch_bounds__(256, 2) void attn(
    const __hip_bfloat16* __restrict__ Q, const __hip_bfloat16* __restrict__ K,
    const __hip_bfloat16* __restrict__ VT, __hip_bfloat16* __restrict__ O) {
  const int tid = threadIdx.x;
  const int wave = tid >> 6, lane = tid & 63;
  const int l16 = lane & 15, quad = lane >> 4;
  const int bh = blockIdx.z * Hh + blockIdx.y;

  const __hip_bfloat16* Qh = Q + (size_t)bh * Tt * Dd;
  const __hip_bfloat16* Kh = K + (size_t)bh * Tt * Dd;
  const __hip_bfloat16* Vh = VT + (size_t)bh * Dd * Tt;
  __hip_bfloat16* Oh = O + (size_t)bh * Tt * Dd;

  __shared__ __align__(16) __bf16 Kt[64 * 72];
  __shared__ __align__(16) __bf16 Vt[64 * 72];
  __shared__ __align__(16) __bf16 Pt[4][2][16 * 72];  // [wave][chain B=0,A=1]

  const float SC = 0.18033688011112042f;  // (1/sqrt(64)) * log2(e)
  const int skey = tid >> 3, sd = (tid & 7) * 8;

  const int qbA = blockIdx.x;           // near q-tile (64-row units)
  const int qbB = (Tt / 64 - 1) - qbA;  // far q-tile
  const int qrowA = qbA * 64 + wave * 16 + l16;
  const int qrowB = qbB * 64 + wave * 16 + l16;

  const bf16x8 qA0 = ldg8(Qh + (size_t)qrowA * Dd + quad * 8);
  const bf16x8 qA1 = ldg8(Qh + (size_t)qrowA * Dd + 32 + quad * 8);
  const bf16x8 qB0 = ldg8(Qh + (size_t)qrowB * Dd + quad * 8);
  const bf16x8 qB1 = ldg8(Qh + (size_t)qrowB * Dd + 32 + quad * 8);

  f32x4 oA[4] = {}, oB[4] = {};
  float lA = 0.f, lB = 0.f;  // per-lane partial denominators

  const int nkB = qbB + 1;

  // Prologue prefetch (tile 0).
  bf16x8 ka = ldg8(Kh + (size_t)skey * Dd + sd);
  bf16x8 kb = ldg8(Kh + (size_t)(32 + skey) * Dd + sd);
  bf16x8 va = ldg8(Vh + (size_t)skey * Tt + sd);
  bf16x8 vb = ldg8(Vh + (size_t)(32 + skey) * Tt + sd);

  for (int kt0 = 0; kt0 < nkB; ++kt0) {
    const int k0 = kt0 * 64;
    __syncthreads();  // all waves done reading previous Kt/Vt
    *reinterpret_cast<bf16x8*>(&Kt[skey * 72 + sd]) = ka;
    *reinterpret_cast<bf16x8*>(&Kt[(32 + skey) * 72 + sd]) = kb;
    *reinterpret_cast<bf16x8*>(&Vt[skey * 72 + sd]) = va;
    *reinterpret_cast<bf16x8*>(&Vt[(32 + skey) * 72 + sd]) = vb;
    if (kt0 + 1 < nkB) {  // prefetch next tile; completes during compute
      const int k1 = k0 + 64;
      ka = ldg8(Kh + (size_t)(k1 + skey) * Dd + sd);
      kb = ldg8(Kh + (size_t)(k1 + 32 + skey) * Dd + sd);
      va = ldg8(Vh + (size_t)skey * Tt + k1 + sd);
      vb = ldg8(Vh + (size_t)(32 + skey) * Tt + k1 + sd);
    }
    __syncthreads();

    const bool doA = (kt0 <= qbA);
    const bool diagB = (kt0 == qbB), diagA = (kt0 == qbA);

    // Shared K fragment reads; S^T = K·Q^T for both chains.
    f32x4 stB[4], stA[4];
#pragma unroll
    for (int kt = 0; kt < 4; ++kt) {
      const __bf16* kr = &Kt[(kt * 16 + l16) * 72 + quad * 8];
      const bf16x8 k0f = lds8(kr), k1f = lds8(kr + 32);
      f32x4 zb = {};
      zb = MFMA16(k0f, qB0, zb);
      stB[kt] = MFMA16(k1f, qB1, zb);
      if (doA) {
        f32x4 za = {};
        za = MFMA16(k0f, qA0, za);
        stA[kt] = MFMA16(k1f, qA1, za);
      }
    }

    // ---- chain B: p = exp2(s*SC) (static max M=0), mask on diag only ----
#pragma unroll
    for (int kt = 0; kt < 4; ++kt) {
      bf16x4 pk;
#pragma unroll
      for (int r = 0; r < 4; ++r) {
        float p = exp2f(stB[kt][r] * SC);
        if (diagB) {
          const int key = k0 + kt * 16 + quad * 4 + r;
          p = (key <= qrowB) ? p : 0.f;
        }
        lB += p;
        pk[r] = (__bf16)p;
      }
      *reinterpret_cast<bf16x4*>(&Pt[wave][0][l16 * 72 + kt * 16 + quad * 4]) = pk;
    }

    // ---- chain A ----
    if (doA) {
#pragma unroll
      for (int kt = 0; kt < 4; ++kt) {
        bf16x4 pk;
#pragma unroll
        for (int r = 0; r < 4; ++r) {
          float p = exp2f(stA[kt][r] * SC);
          if (diagA) {
            const int key = k0 + kt * 16 + quad * 4 + r;
            p = (key <= qrowA) ? p : 0.f;
          }
          lA += p;
          pk[r] = (__bf16)p;
        }
        *reinterpret_cast<bf16x4*>(&Pt[wave][1][l16 * 72 + kt * 16 + quad * 4]) = pk;
      }
    }

    // ---- PV for both chains, sharing V fragment reads ----
    const bf16x8 pB0 = lds8(&Pt[wave][0][l16 * 72 + quad * 8]);
    const bf16x8 pB1 = lds8(&Pt[wave][0][l16 * 72 + 32 + quad * 8]);
    const bf16x8 pA0 = lds8(&Pt[wave][1][l16 * 72 + quad * 8]);
    const bf16x8 pA1 = lds8(&Pt[wave][1][l16 * 72 + 32 + quad * 8]);
#pragma unroll
    for (int dt = 0; dt < 4; ++dt) {
      const __bf16* vr = &Vt[(dt * 16 + l16) * 72];
      const bf16x8 v0f = lds8(vr + quad * 8), v1f = lds8(vr + 32 + quad * 8);
      oB[dt] = MFMA16(v0f, pB0, oB[dt]);
      oB[dt] = MFMA16(v1f, pB1, oB[dt]);
      if (doA) {
        oA[dt] = MFMA16(v0f, pA0, oA[dt]);
        oA[dt] = MFMA16(v1f, pA1, oA[dt]);
      }
    }
  }

  // One cross-lane reduction per chain for the denominators.
  lA += __shfl_xor(lA, 16, 64);
  lA += __shfl_xor(lA, 32, 64);
  lB += __shfl_xor(lB, 16, 64);
  lB += __shfl_xor(lB, 32, 64);

  const float invA = 1.f / lA, invB = 1.f / lB;
#pragma unroll
  for (int dt = 0; dt < 4; ++dt) {
    bf16x4 ovA, ovB;
#pragma unroll
    for (int r = 0; r < 4; ++r) {
      ovA[r] = (__bf16)(oA[dt][r] * invA);
      ovB[r] = (__bf16)(oB[dt][r] * invB);
    }
    *reinterpret_cast<bf16x4*>(&Oh[(size_t)qrowA * Dd + dt * 16 + quad * 4]) = ovA;
    *reinterpret_cast<bf16x4*>(&Oh[(size_t)qrowB * Dd + dt * 16 + quad * 4]) = ovB;
  }
}

// ---------------------------------------------------------------------------
// Proj GEMM (m97 structure): y(f32)[4096,1024] = O([B,H,T,D]) @ WT[1024,1024]^T + b
// ---------------------------------------------------------------------------
__global__ __launch_bounds__(256) void proj_gemm(
    const __hip_bfloat16* __restrict__ O, const __hip_bfloat16* __restrict__ WT,
    const float* __restrict__ bias, float* __restrict__ out) {
  __shared__ __hip_bfloat16 As[128 * 32];
  __shared__ __hip_bfloat16 Bs[128 * 32];
  const int tid = threadIdx.x;
  const int wave = tid >> 6, lane = tid & 63;
  const int l16 = lane & 15, quad = lane >> 4;
  const int m0 = blockIdx.y * 128, n0 = blockIdx.x * 128;
  const int wm = (wave >> 1) * 64, wn = (wave & 1) * 64;

  const int srow = wave * 32 + (lane >> 2);
  const int kseg = (lane & 3) * 8;

  f32x4 acc[4][4] = {};

  for (int k0 = 0; k0 < Cc; k0 += 32) {
    const int k = k0 + kseg;  // channel = h*64+d; 8-seg never crosses a head
    const int h = k >> 6, d = k & 63;
    __syncthreads();
#pragma unroll
    for (int j = 0; j < 2; ++j) {
      const int m = m0 + srow + j * 16;
      const int b = m >> 11, t = m & 2047;
      load_lds16(O + ((size_t)(b * Hh + h) * Tt + t) * Dd + d,
                 As + (wave * 32 + j * 16) * 32);
      load_lds16(WT + (size_t)(n0 + srow + j * 16) * Cc + k0 + kseg,
                 Bs + (wave * 32 + j * 16) * 32);
    }
    __syncthreads();

    bf16x8 af[4], bfr[4];
#pragma unroll
    for (int i = 0; i < 4; ++i) {
      af[i] = ldg8(As + (wm + i * 16 + l16) * 32 + quad * 8);
      bfr[i] = ldg8(Bs + (wn + i * 16 + l16) * 32 + quad * 8);
    }
#pragma unroll
    for (int i = 0; i < 4; ++i)
#pragma unroll
      for (int jn = 0; jn < 4; ++jn)
        acc[i][jn] = MFMA16(af[i], bfr[jn], acc[i][jn]);
  }

#pragma unroll
  for (int jn = 0; jn < 4; ++jn) {
    const int n = n0 + wn + jn * 16 + l16;
    const float bv = bias[n];
#pragma unroll
    for (int i = 0; i < 4; ++i)
#pragma unroll
      for (int r = 0; r < 4; ++r) {
        const int m = m0 + wm + i * 16 + quad * 4 + r;
        out[(size_t)m * Cc + n] = acc[i][jn][r] + bv;
      }
  }
}

// ---------------------------------------------------------------------------
extern "C" void kernel_launch(void* const* d_in, const int* in_sizes, int n_in,
                              void* d_out, int out_size, void* d_ws, size_t ws_size,
                              hipStream_t stream) {
  const float* x      = (const float*)d_in[0];
  const float* W_qkv  = (const float*)d_in[1];
  const float* b_qkv  = (const float*)d_in[2];
  const float* W_proj = (const float*)d_in[3];
  const float* b_proj = (const float*)d_in[4];
  float* out = (float*)d_out;

  __hip_bfloat16* ws = (__hip_bfloat16*)d_ws;
  const size_t NBHTD = (size_t)Bb * Hh * Tt * Dd;  // 4,194,304
  __hip_bfloat16* Qw  = ws;
  __hip_bfloat16* Kw  = ws + NBHTD;
  __hip_bfloat16* VTw = ws + 2 * NBHTD;
  __hip_bfloat16* Ow  = ws + 3 * NBHTD;
  __hip_bfloat16* WTqkv  = ws + 4 * NBHTD;               // [3072,1024]
  __hip_bfloat16* WTproj = WTqkv + (size_t)3 * Cc * Cc;  // [1024,1024]

  prep_weights<<<dim3(128, 32), dim3(32, 8), 0, stream>>>(W_qkv, W_proj, WTqkv, WTproj);
  qkv_gemm<<<dim3(24, 32), 256, 0, stream>>>(x, WTqkv, b_qkv, Qw, Kw, VTw);
  attn<<<dim3(Tt / 128, Hh, Bb), 256, 0, stream>>>(Qw, Kw, VTw, Ow);
  proj_gemm<<<dim3(8, 32), 256, 0, stream>>>(Ow, WTproj, b_proj, out);
}

// Round 13
// 189.222 us; speedup vs baseline: 1.2365x; 1.1318x over previous
//
#include <hip/hip_runtime.h>
#include <hip/hip_bf16.h>

// Problem: B=2, T=2048, C=1024, H=16, D=64. Tensors stored f32; compute bf16 MFMA.
#define Bb 2
#define Tt 2048
#define Cc 1024
#define Hh 16
#define Dd 64

typedef __bf16 bf16x8 __attribute__((ext_vector_type(8)));
typedef __bf16 bf16x4 __attribute__((ext_vector_type(4)));
typedef float f32x4 __attribute__((ext_vector_type(4)));

#define MFMA16(a, b, c) __builtin_amdgcn_mfma_f32_16x16x32_bf16((a), (b), (c), 0, 0, 0)

__device__ __forceinline__ bf16x8 ldg8(const __hip_bfloat16* p) {
  return *reinterpret_cast<const bf16x8*>(p);
}
__device__ __forceinline__ bf16x8 lds8(const __bf16* p) {
  return *reinterpret_cast<const bf16x8*>(p);
}

// Async global->LDS, 16B per lane. LDS dest = wave-uniform base + lane*16.
__device__ __forceinline__ void load_lds16(const __hip_bfloat16* g, __hip_bfloat16* l) {
  __builtin_amdgcn_global_load_lds(
      (const __attribute__((address_space(1))) void*)g,
      (__attribute__((address_space(3))) void*)l, 16, 0, 0);
}

// ---------------------------------------------------------------------------
// prep: W_qkv transpose+cast (bx 0..95), W_proj transpose+cast (bx 96..127),
// x f32->bf16 cvt (bx 128..255, with by as sub-index). One launch.
// ---------------------------------------------------------------------------
__global__ __launch_bounds__(256) void prep_inputs(
    const float* __restrict__ Wq, const float* __restrict__ Wp,
    const float* __restrict__ x,
    __hip_bfloat16* __restrict__ WTq, __hip_bfloat16* __restrict__ WTp,
    __hip_bfloat16* __restrict__ xb) {
  const int bx = blockIdx.x;
  const int tx = threadIdx.x, ty = threadIdx.y;  // block (32,8)
  if (bx >= 128) {
    // x cvt: 4096 virtual blocks of 1024 elems.
    const int vb = (bx - 128) * 32 + blockIdx.y;
    const int tid = ty * 32 + tx;
    const int i = (vb * 256 + tid) * 4;
    const float4 v = *reinterpret_cast<const float4*>(x + i);
    xb[i + 0] = __float2bfloat16(v.x);
    xb[i + 1] = __float2bfloat16(v.y);
    xb[i + 2] = __float2bfloat16(v.z);
    xb[i + 3] = __float2bfloat16(v.w);
    return;
  }
  __shared__ float tile[32][33];
  const bool isQ = bx < 96;
  const float* in = isQ ? Wq : Wp;
  __hip_bfloat16* out = isQ ? WTq : WTp;
  const int Cn = isQ ? 3 * Cc : Cc;
  const int c0 = (isQ ? bx : bx - 96) * 32;
  const int r0 = blockIdx.y * 32;
#pragma unroll
  for (int i = 0; i < 32; i += 8)
    tile[ty + i][tx] = in[(size_t)(r0 + ty + i) * Cn + c0 + tx];
  __syncthreads();
#pragma unroll
  for (int i = 0; i < 32; i += 8)
    out[(size_t)(c0 + ty + i) * Cc + r0 + tx] = __float2bfloat16(tile[tx][ty + i]);
}

// ---------------------------------------------------------------------------
// QKV GEMM (R10 known-good m97 structure): xb[4096,1024] @ WT[3072,1024]^T + b
//   -> Q,K [B,H,T,D] bf16, V^T [B,H,D,T] bf16. Both tiles via global_load_lds.
// ---------------------------------------------------------------------------
__global__ __launch_bounds__(256) void qkv_gemm(
    const __hip_bfloat16* __restrict__ x, const __hip_bfloat16* __restrict__ WT,
    const float* __restrict__ bias,
    __hip_bfloat16* __restrict__ Q, __hip_bfloat16* __restrict__ Kd,
    __hip_bfloat16* __restrict__ VT) {
  __shared__ __hip_bfloat16 As[128 * 32];
  __shared__ __hip_bfloat16 Bs[128 * 32];
  const int tid = threadIdx.x;
  const int wave = tid >> 6, lane = tid & 63;
  const int l16 = lane & 15, quad = lane >> 4;
  const int m0 = blockIdx.y * 128, n0 = blockIdx.x * 128;
  const int wm = (wave >> 1) * 64, wn = (wave & 1) * 64;

  const int srow = wave * 32 + (lane >> 2);
  const int kseg = (lane & 3) * 8;

  f32x4 acc[4][4] = {};

  for (int k0 = 0; k0 < Cc; k0 += 32) {
    __syncthreads();
#pragma unroll
    for (int j = 0; j < 2; ++j) {
      load_lds16(x + (size_t)(m0 + srow + j * 16) * Cc + k0 + kseg,
                 As + (wave * 32 + j * 16) * 32);
      load_lds16(WT + (size_t)(n0 + srow + j * 16) * Cc + k0 + kseg,
                 Bs + (wave * 32 + j * 16) * 32);
    }
    __syncthreads();

    bf16x8 af[4], bfr[4];
#pragma unroll
    for (int i = 0; i < 4; ++i) {
      af[i] = ldg8(As + (wm + i * 16 + l16) * 32 + quad * 8);
      bfr[i] = ldg8(Bs + (wn + i * 16 + l16) * 32 + quad * 8);
    }
#pragma unroll
    for (int i = 0; i < 4; ++i)
#pragma unroll
      for (int jn = 0; jn < 4; ++jn)
        acc[i][jn] = MFMA16(af[i], bfr[jn], acc[i][jn]);
  }

  const int sect = n0 >> 10;  // 0=Q 1=K 2=V (uniform per block)
#pragma unroll
  for (int jn = 0; jn < 4; ++jn) {
    const int n = n0 + wn + jn * 16 + l16;
    const float bv = bias[n];
    const int ch = n & 1023;
    const int h = ch >> 6, d = ch & 63;
#pragma unroll
    for (int i = 0; i < 4; ++i) {
#pragma unroll
      for (int r = 0; r < 4; ++r) {
        const int m = m0 + wm + i * 16 + quad * 4 + r;
        const int b = m >> 11, t = m & 2047;
        const __hip_bfloat16 o = __float2bfloat16(acc[i][jn][r] + bv);
        const int bh = b * Hh + h;
        if (sect == 0)      Q[((size_t)bh * Tt + t) * Dd + d] = o;
        else if (sect == 1) Kd[((size_t)bh * Tt + t) * Dd + d] = o;
        else                VT[((size_t)bh * Dd + d) * Tt + t] = o;
      }
    }
  }
}

// ---------------------------------------------------------------------------
// Flash attention v8 (unchanged): static-max softmax, merged causal pair
// {qb, 31-qb}, register prefetch, shared K/V LDS reads for both chains.
// ---------------------------------------------------------------------------
__global__ __launch_bounds__(256, 2) void attn(
    const __hip_bfloat16* __restrict__ Q, const __hip_bfloat16* __restrict__ K,
    const __hip_bfloat16* __restrict__ VT, __hip_bfloat16* __restrict__ O) {
  const int tid = threadIdx.x;
  const int wave = tid >> 6, lane = tid & 63;
  const int l16 = lane & 15, quad = lane >> 4;
  const int bh = blockIdx.z * Hh + blockIdx.y;

  const __hip_bfloat16* Qh = Q + (size_t)bh * Tt * Dd;
  const __hip_bfloat16* Kh = K + (size_t)bh * Tt * Dd;
  const __hip_bfloat16* Vh = VT + (size_t)bh * Dd * Tt;
  __hip_bfloat16* Oh = O + (size_t)bh * Tt * Dd;

  __shared__ __align__(16) __bf16 Kt[64 * 72];
  __shared__ __align__(16) __bf16 Vt[64 * 72];
  __shared__ __align__(16) __bf16 Pt[4][2][16 * 72];  // [wave][chain B=0,A=1]

  const float SC = 0.18033688011112042f;  // (1/sqrt(64)) * log2(e)
  const int skey = tid >> 3, sd = (tid & 7) * 8;

  const int qbA = blockIdx.x;           // near q-tile (64-row units)
  const int qbB = (Tt / 64 - 1) - qbA;  // far q-tile
  const int qrowA = qbA * 64 + wave * 16 + l16;
  const int qrowB = qbB * 64 + wave * 16 + l16;

  const bf16x8 qA0 = ldg8(Qh + (size_t)qrowA * Dd + quad * 8);
  const bf16x8 qA1 = ldg8(Qh + (size_t)qrowA * Dd + 32 + quad * 8);
  const bf16x8 qB0 = ldg8(Qh + (size_t)qrowB * Dd + quad * 8);
  const bf16x8 qB1 = ldg8(Qh + (size_t)qrowB * Dd + 32 + quad * 8);

  f32x4 oA[4] = {}, oB[4] = {};
  float lA = 0.f, lB = 0.f;  // per-lane partial denominators

  const int nkB = qbB + 1;

  // Prologue prefetch (tile 0).
  bf16x8 ka = ldg8(Kh + (size_t)skey * Dd + sd);
  bf16x8 kb = ldg8(Kh + (size_t)(32 + skey) * Dd + sd);
  bf16x8 va = ldg8(Vh + (size_t)skey * Tt + sd);
  bf16x8 vb = ldg8(Vh + (size_t)(32 + skey) * Tt + sd);

  for (int kt0 = 0; kt0 < nkB; ++kt0) {
    const int k0 = kt0 * 64;
    __syncthreads();  // all waves done reading previous Kt/Vt
    *reinterpret_cast<bf16x8*>(&Kt[skey * 72 + sd]) = ka;
    *reinterpret_cast<bf16x8*>(&Kt[(32 + skey) * 72 + sd]) = kb;
    *reinterpret_cast<bf16x8*>(&Vt[skey * 72 + sd]) = va;
    *reinterpret_cast<bf16x8*>(&Vt[(32 + skey) * 72 + sd]) = vb;
    if (kt0 + 1 < nkB) {  // prefetch next tile; completes during compute
      const int k1 = k0 + 64;
      ka = ldg8(Kh + (size_t)(k1 + skey) * Dd + sd);
      kb = ldg8(Kh + (size_t)(k1 + 32 + skey) * Dd + sd);
      va = ldg8(Vh + (size_t)skey * Tt + k1 + sd);
      vb = ldg8(Vh + (size_t)(32 + skey) * Tt + k1 + sd);
    }
    __syncthreads();

    const bool doA = (kt0 <= qbA);
    const bool diagB = (kt0 == qbB), diagA = (kt0 == qbA);

    // Shared K fragment reads; S^T = K·Q^T for both chains.
    f32x4 stB[4], stA[4];
#pragma unroll
    for (int kt = 0; kt < 4; ++kt) {
      const __bf16* kr = &Kt[(kt * 16 + l16) * 72 + quad * 8];
      const bf16x8 k0f = lds8(kr), k1f = lds8(kr + 32);
      f32x4 zb = {};
      zb = MFMA16(k0f, qB0, zb);
      stB[kt] = MFMA16(k1f, qB1, zb);
      if (doA) {
        f32x4 za = {};
        za = MFMA16(k0f, qA0, za);
        stA[kt] = MFMA16(k1f, qA1, za);
      }
    }

    // ---- chain B: p = exp2(s*SC) (static max M=0), mask on diag only ----
#pragma unroll
    for (int kt = 0; kt < 4; ++kt) {
      bf16x4 pk;
#pragma unroll
      for (int r = 0; r < 4; ++r) {
        float p = exp2f(stB[kt][r] * SC);
        if (diagB) {
          const int key = k0 + kt * 16 + quad * 4 + r;
          p = (key <= qrowB) ? p : 0.f;
        }
        lB += p;
        pk[r] = (__bf16)p;
      }
      *reinterpret_cast<bf16x4*>(&Pt[wave][0][l16 * 72 + kt * 16 + quad * 4]) = pk;
    }

    // ---- chain A ----
    if (doA) {
#pragma unroll
      for (int kt = 0; kt < 4; ++kt) {
        bf16x4 pk;
#pragma unroll
        for (int r = 0; r < 4; ++r) {
          float p = exp2f(stA[kt][r] * SC);
          if (diagA) {
            const int key = k0 + kt * 16 + quad * 4 + r;
            p = (key <= qrowA) ? p : 0.f;
          }
          lA += p;
          pk[r] = (__bf16)p;
        }
        *reinterpret_cast<bf16x4*>(&Pt[wave][1][l16 * 72 + kt * 16 + quad * 4]) = pk;
      }
    }

    // ---- PV for both chains, sharing V fragment reads ----
    const bf16x8 pB0 = lds8(&Pt[wave][0][l16 * 72 + quad * 8]);
    const bf16x8 pB1 = lds8(&Pt[wave][0][l16 * 72 + 32 + quad * 8]);
    const bf16x8 pA0 = lds8(&Pt[wave][1][l16 * 72 + quad * 8]);
    const bf16x8 pA1 = lds8(&Pt[wave][1][l16 * 72 + 32 + quad * 8]);
#pragma unroll
    for (int dt = 0; dt < 4; ++dt) {
      const __bf16* vr = &Vt[(dt * 16 + l16) * 72];
      const bf16x8 v0f = lds8(vr + quad * 8), v1f = lds8(vr + 32 + quad * 8);
      oB[dt] = MFMA16(v0f, pB0, oB[dt]);
      oB[dt] = MFMA16(v1f, pB1, oB[dt]);
      if (doA) {
        oA[dt] = MFMA16(v0f, pA0, oA[dt]);
        oA[dt] = MFMA16(v1f, pA1, oA[dt]);
      }
    }
  }

  // One cross-lane reduction per chain for the denominators.
  lA += __shfl_xor(lA, 16, 64);
  lA += __shfl_xor(lA, 32, 64);
  lB += __shfl_xor(lB, 16, 64);
  lB += __shfl_xor(lB, 32, 64);

  const float invA = 1.f / lA, invB = 1.f / lB;
#pragma unroll
  for (int dt = 0; dt < 4; ++dt) {
    bf16x4 ovA, ovB;
#pragma unroll
    for (int r = 0; r < 4; ++r) {
      ovA[r] = (__bf16)(oA[dt][r] * invA);
      ovB[r] = (__bf16)(oB[dt][r] * invB);
    }
    *reinterpret_cast<bf16x4*>(&Oh[(size_t)qrowA * Dd + dt * 16 + quad * 4]) = ovA;
    *reinterpret_cast<bf16x4*>(&Oh[(size_t)qrowB * Dd + dt * 16 + quad * 4]) = ovB;
  }
}

// ---------------------------------------------------------------------------
// Proj GEMM (m97 structure): y(f32)[4096,1024] = O([B,H,T,D]) @ WT[1024,1024]^T + b
// ---------------------------------------------------------------------------
__global__ __launch_bounds__(256) void proj_gemm(
    const __hip_bfloat16* __restrict__ O, const __hip_bfloat16* __restrict__ WT,
    const float* __restrict__ bias, float* __restrict__ out) {
  __shared__ __hip_bfloat16 As[128 * 32];
  __shared__ __hip_bfloat16 Bs[128 * 32];
  const int tid = threadIdx.x;
  const int wave = tid >> 6, lane = tid & 63;
  const int l16 = lane & 15, quad = lane >> 4;
  const int m0 = blockIdx.y * 128, n0 = blockIdx.x * 128;
  const int wm = (wave >> 1) * 64, wn = (wave & 1) * 64;

  const int srow = wave * 32 + (lane >> 2);
  const int kseg = (lane & 3) * 8;

  f32x4 acc[4][4] = {};

  for (int k0 = 0; k0 < Cc; k0 += 32) {
    const int k = k0 + kseg;  // channel = h*64+d; 8-seg never crosses a head
    const int h = k >> 6, d = k & 63;
    __syncthreads();
#pragma unroll
    for (int j = 0; j < 2; ++j) {
      const int m = m0 + srow + j * 16;
      const int b = m >> 11, t = m & 2047;
      load_lds16(O + ((size_t)(b * Hh + h) * Tt + t) * Dd + d,
                 As + (wave * 32 + j * 16) * 32);
      load_lds16(WT + (size_t)(n0 + srow + j * 16) * Cc + k0 + kseg,
                 Bs + (wave * 32 + j * 16) * 32);
    }
    __syncthreads();

    bf16x8 af[4], bfr[4];
#pragma unroll
    for (int i = 0; i < 4; ++i) {
      af[i] = ldg8(As + (wm + i * 16 + l16) * 32 + quad * 8);
      bfr[i] = ldg8(Bs + (wn + i * 16 + l16) * 32 + quad * 8);
    }
#pragma unroll
    for (int i = 0; i < 4; ++i)
#pragma unroll
      for (int jn = 0; jn < 4; ++jn)
        acc[i][jn] = MFMA16(af[i], bfr[jn], acc[i][jn]);
  }

#pragma unroll
  for (int jn = 0; jn < 4; ++jn) {
    const int n = n0 + wn + jn * 16 + l16;
    const float bv = bias[n];
#pragma unroll
    for (int i = 0; i < 4; ++i)
#pragma unroll
      for (int r = 0; r < 4; ++r) {
        const int m = m0 + wm + i * 16 + quad * 4 + r;
        out[(size_t)m * Cc + n] = acc[i][jn][r] + bv;
      }
  }
}

// ---------------------------------------------------------------------------
extern "C" void kernel_launch(void* const* d_in, const int* in_sizes, int n_in,
                              void* d_out, int out_size, void* d_ws, size_t ws_size,
                              hipStream_t stream) {
  const float* x      = (const float*)d_in[0];
  const float* W_qkv  = (const float*)d_in[1];
  const float* b_qkv  = (const float*)d_in[2];
  const float* W_proj = (const float*)d_in[3];
  const float* b_proj = (const float*)d_in[4];
  float* out = (float*)d_out;

  __hip_bfloat16* ws = (__hip_bfloat16*)d_ws;
  const size_t NBHTD = (size_t)Bb * Hh * Tt * Dd;  // 4,194,304
  __hip_bfloat16* Qw  = ws;
  __hip_bfloat16* Kw  = ws + NBHTD;
  __hip_bfloat16* VTw = ws + 2 * NBHTD;
  __hip_bfloat16* Ow  = ws + 3 * NBHTD;
  __hip_bfloat16* xb  = ws + 4 * NBHTD;                  // [4096,1024]
  __hip_bfloat16* WTqkv  = xb + NBHTD;                   // [3072,1024]
  __hip_bfloat16* WTproj = WTqkv + (size_t)3 * Cc * Cc;  // [1024,1024]

  prep_inputs<<<dim3(256, 32), dim3(32, 8), 0, stream>>>(W_qkv, W_proj, x,
                                                         WTqkv, WTproj, xb);
  qkv_gemm<<<dim3(24, 32), 256, 0, stream>>>(xb, WTqkv, b_qkv, Qw, Kw, VTw);
  attn<<<dim3(Tt / 128, Hh, Bb), 256, 0, stream>>>(Qw, Kw, VTw, Ow);
  proj_gemm<<<dim3(8, 32), 256, 0, stream>>>(Ow, WTproj, b_proj, out);
}